// Round 2
// baseline (1082.359 us; speedup 1.0000x reference)
//
#include <hip/hip_runtime.h>
#include <cstdint>
#include <cstddef>

#define B_   128
#define NCH  64
#define T_   30720
#define TT   64           // time-steps per LDS tile
#define EPSF 1e-12f
#define THRF 0.5f

typedef float f32x4 __attribute__((ext_vector_type(4)));

// ---------------------------------------------------------------------------
// Stage 1: per (batch, T-chunk) block computes
//   P[b,c][n][m] = sum_{t in chunk} x[b][n][t] * x[b][m][t]   (64x64)
//   S[b,c][n]    = sum_{t in chunk} x[b][n][t]
// and streams the x tile through to out_x (the passthrough output).
// 256 threads = 4 waves. Tile [64 ch][64 t] staged in LDS (XOR-swizzled).
// Each wave handles 4 of the 16 time-quads; each lane owns an 8x8 block of
// the 64x64 output (8x8 lane grid), reading 2x8 f32x4 per quad -> 256 FMAs.
// ---------------------------------------------------------------------------
__global__ __launch_bounds__(256) void corr_stage1(
    const float* __restrict__ x, float* __restrict__ out_x,
    float* __restrict__ P, float* __restrict__ S,
    int split, int Tc)
{
    __shared__ float lds[NCH * TT];   // 16 KB; reused for final reductions

    const int tid  = threadIdx.x;
    const int lane = tid & 63;
    const int w    = tid >> 6;        // wave id 0..3
    const int ri   = lane >> 3;       // row-block 0..7
    const int ci   = lane & 7;        // col-block 0..7

    const int bid = blockIdx.x;
    const int b   = bid / split;
    const int c   = bid - b * split;

    const int ch_st = tid >> 2;       // staging channel 0..63
    const int j_st  = tid & 3;        // staging sub-index 0..3

    const size_t base = (size_t)b * ((size_t)NCH * T_) + (size_t)c * Tc;
    const float* xb = x + base;
    float*       ob = out_x + base;

    float acc[8][8];
    #pragma unroll
    for (int a = 0; a < 8; ++a)
        #pragma unroll
        for (int e = 0; e < 8; ++e) acc[a][e] = 0.f;
    float ssum = 0.f;

    const int sw_st = ((ch_st >> 3) ^ ch_st) & 7;
    const int ntile = Tc / TT;

    for (int tile = 0; tile < ntile; ++tile) {
        const int tbase = tile * TT;
        __syncthreads();   // previous compute done before overwriting tile
        // ---- stage global -> LDS (+ fused copy to out_x) ----
        #pragma unroll
        for (int i = 0; i < 4; ++i) {
            const int q = 4 * i + j_st;               // quad 0..15 (coalesced per instr)
            const size_t goff = (size_t)ch_st * T_ + tbase + q * 4;
            const f32x4 v = *reinterpret_cast<const f32x4*>(xb + goff);
            __builtin_nontemporal_store(v, reinterpret_cast<f32x4*>(ob + goff));
            ssum += v.x + v.y + v.z + v.w;
            *reinterpret_cast<f32x4*>(&lds[ch_st * TT + ((q ^ sw_st) << 2)]) = v;
        }
        __syncthreads();
        // ---- compute: wave w handles quads 4w .. 4w+3 ----
        #pragma unroll
        for (int qi = 0; qi < 4; ++qi) {
            const int q = (w << 2) + qi;
            f32x4 R[8];
            #pragma unroll
            for (int k = 0; k < 8; ++k) {
                const int chr = (ri << 3) + k;
                const int sw  = ((chr >> 3) ^ chr) & 7;
                R[k] = *reinterpret_cast<const f32x4*>(&lds[chr * TT + ((q ^ sw) << 2)]);
            }
            #pragma unroll
            for (int half = 0; half < 2; ++half) {
                f32x4 C[4];
                #pragma unroll
                for (int k = 0; k < 4; ++k) {
                    const int chc = (ci << 3) + (half << 2) + k;
                    const int sw  = ((chc >> 3) ^ chc) & 7;
                    C[k] = *reinterpret_cast<const f32x4*>(&lds[chc * TT + ((q ^ sw) << 2)]);
                }
                #pragma unroll
                for (int a = 0; a < 8; ++a)
                    #pragma unroll
                    for (int e = 0; e < 4; ++e) {
                        const int col = (half << 2) + e;
                        acc[a][col] += R[a].x * C[e].x + R[a].y * C[e].y
                                     + R[a].z * C[e].z + R[a].w * C[e].w;
                    }
            }
        }
    }

    // ---- S reduction (4 partial sums per channel) ----
    __syncthreads();
    lds[tid] = ssum;
    __syncthreads();
    if (tid < NCH) {
        const float s4 = lds[4 * tid] + lds[4 * tid + 1] + lds[4 * tid + 2] + lds[4 * tid + 3];
        S[(size_t)(b * split + c) * NCH + tid] = s4;
    }
    __syncthreads();

    // ---- G reduction across the 4 waves (phased, deterministic) ----
    for (int wp = 0; wp < 4; ++wp) {
        if (w == wp) {
            #pragma unroll
            for (int a = 0; a < 8; ++a)
                #pragma unroll
                for (int e = 0; e < 8; ++e) {
                    const int row = (ri << 3) + a;
                    const int col = (ci << 3) + e;
                    const int idx = (row << 6) + col;
                    if (wp == 0) lds[idx] = acc[a][e];
                    else         lds[idx] += acc[a][e];
                }
        }
        __syncthreads();
    }

    float* Pc = P + ((size_t)(b * split + c) << 12);
    for (int i = tid; i < 4096; i += 256) Pc[i] = lds[i];
}

// ---------------------------------------------------------------------------
// Stage 2: combine chunk partials -> corr -> threshold -> adj
// ---------------------------------------------------------------------------
__global__ __launch_bounds__(256) void corr_stage2(
    const float* __restrict__ P, const float* __restrict__ S,
    float* __restrict__ adj, int split)
{
    const int idx = blockIdx.x * 256 + threadIdx.x;   // < 128*4096
    const int b  = idx >> 12;
    const int nm = idx & 4095;
    const int n  = nm >> 6;
    const int m  = nm & 63;

    float G = 0.f, Gnn = 0.f, Gmm = 0.f, Sn = 0.f, Sm = 0.f;
    for (int c = 0; c < split; ++c) {
        const float* Pc = P + ((size_t)(b * split + c) << 12);
        const float* Sc = S + (size_t)(b * split + c) * NCH;
        G   += Pc[nm];
        Gnn += Pc[n * 65];
        Gmm += Pc[m * 65];
        Sn  += Sc[n];
        Sm  += Sc[m];
    }
    const float invT = 1.0f / (float)T_;
    const float cov  = G   - Sn * Sm * invT;
    const float vn   = Gnn - Sn * Sn * invT;
    const float vm   = Gmm - Sm * Sm * invT;
    const float den  = sqrtf(vn) * sqrtf(vm) + EPSF;
    float corr = cov / den;
    if (n == m) corr = 0.f;
    adj[idx] = (fabsf(corr) >= THRF) ? corr : 0.f;
}

// ---------------------------------------------------------------------------
extern "C" void kernel_launch(void* const* d_in, const int* in_sizes, int n_in,
                              void* d_out, int out_size, void* d_ws, size_t ws_size,
                              hipStream_t stream)
{
    const float* x   = (const float*)d_in[0];
    float* out   = (float*)d_out;
    float* adj   = out;                                  // 128*64*64
    float* out_x = out + (size_t)B_ * NCH * NCH;         // passthrough x

    // workspace: P = [128*split][4096] f32, S = [128*split][64] f32
    int split = 8;
    while (split > 1 &&
           (size_t)B_ * split * (4096 + NCH) * sizeof(float) > ws_size)
        split >>= 1;

    float* P = (float*)d_ws;
    float* S = P + (size_t)B_ * split * 4096;
    const int Tc = T_ / split;

    corr_stage1<<<dim3(B_ * split), dim3(256), 0, stream>>>(x, out_x, P, S, split, Tc);
    corr_stage2<<<dim3((B_ * 4096) / 256), dim3(256), 0, stream>>>(P, S, adj, split);
}

// Round 3
// 481.478 us; speedup vs baseline: 2.2480x; 2.2480x over previous
//
#include <hip/hip_runtime.h>
#include <cstdint>
#include <cstddef>

#define B_   128
#define NCH  64
#define T_   30720
#define TT   128          // time-steps per LDS tile (4 K-steps of 32)
#define EPSF 1e-12f
#define THRF 0.5f

typedef float  f32x4 __attribute__((ext_vector_type(4)));
typedef short  s16x8 __attribute__((ext_vector_type(8)));
typedef unsigned short u16;

// round-to-nearest-even f32 -> bf16 bits, also returns the rounded value as f32
static __device__ __forceinline__ u16 bf16_rne(float f, float& as_f32) {
    unsigned u = __builtin_bit_cast(unsigned, f);
    unsigned r = (u + 0x7FFFu + ((u >> 16) & 1u)) >> 16;
    as_f32 = __builtin_bit_cast(float, r << 16);
    return (u16)r;
}

// ---------------------------------------------------------------------------
// Stage 1: per (batch, T-chunk) block:
//   - stream x tile HBM -> LDS (bf16 hi+lo planes) + fused copy to out_x
//   - MFMA Gram: P[b,c] = sum_t x x^T  via  hi*hi + hi*lo + lo*hi
//   - S[b,c][n] = sum_t x[n][t]
// 256 threads = 4 waves; wave w owns rows w*16..w*16+15 of the 64x64 output
// (4 fragments of 16x16, K accumulated over the whole chunk).
// LDS planes [64][128] bf16, XOR-swizzled at 16B granularity: byte ^= (row&7)<<4.
// ---------------------------------------------------------------------------
__global__ __launch_bounds__(256) void corr_stage1(
    const float* __restrict__ x, float* __restrict__ out_x,
    float* __restrict__ P, float* __restrict__ S,
    int split, int Tc)
{
    __shared__ __align__(16) u16 ldsH[NCH * TT];   // 16 KB hi plane
    __shared__ __align__(16) u16 ldsL[NCH * TT];   // 16 KB lo plane

    const int tid  = threadIdx.x;
    const int lane = tid & 63;
    const int w    = tid >> 6;            // wave 0..3

    const int bid = blockIdx.x;
    const int b   = bid / split;
    const int c   = bid - b * split;

    const size_t base = (size_t)b * ((size_t)NCH * T_) + (size_t)c * Tc;
    const float* xb = x + base;
    float*       ob = out_x + base;

    // staging mapping: 16 channels x 16 groups-of-8 floats per pass, 4 passes
    const int sch = tid >> 4;             // 0..15 (channel within pass group)
    const int sg  = tid & 15;             // group: t = sg*8 .. sg*8+7

    // MFMA fragment addressing
    const int r    = lane & 15;           // row within fragment
    const int koff = (lane >> 4) << 4;    // byte offset of this lane's 8 bf16 in K
    const int swz  = (r & 7) << 4;        // row XOR swizzle

    f32x4 acc[4];
    #pragma unroll
    for (int fn = 0; fn < 4; ++fn) acc[fn] = (f32x4)(0.f);
    float ssum[4] = {0.f, 0.f, 0.f, 0.f};

    const int ntile = Tc / TT;

    for (int tile = 0; tile < ntile; ++tile) {
        const int tbase = tile * TT;
        __syncthreads();   // previous tile's reads done before overwrite
        // ---- stage: global -> (copy out, bf16 hi/lo -> LDS) ----
        #pragma unroll
        for (int p = 0; p < 4; ++p) {
            const int ch = p * 16 + sch;
            const size_t go = (size_t)ch * T_ + (size_t)(tbase + sg * 8);
            const f32x4 v0 = *reinterpret_cast<const f32x4*>(xb + go);
            const f32x4 v1 = *reinterpret_cast<const f32x4*>(xb + go + 4);
            __builtin_nontemporal_store(v0, reinterpret_cast<f32x4*>(ob + go));
            __builtin_nontemporal_store(v1, reinterpret_cast<f32x4*>(ob + go + 4));
            float e[8] = {v0.x, v0.y, v0.z, v0.w, v1.x, v1.y, v1.z, v1.w};
            s16x8 hv, lv;
            #pragma unroll
            for (int j = 0; j < 8; ++j) {
                float hf, dummy;
                const u16 hb = bf16_rne(e[j], hf);
                const u16 lb = bf16_rne(e[j] - hf, dummy);
                hv[j] = (short)hb;
                lv[j] = (short)lb;
                ssum[p] += e[j];
            }
            const int ba = ch * (TT * 2) + ((sg * 16) ^ ((ch & 7) << 4));
            *reinterpret_cast<s16x8*>(reinterpret_cast<char*>(ldsH) + ba) = hv;
            *reinterpret_cast<s16x8*>(reinterpret_cast<char*>(ldsL) + ba) = lv;
        }
        __syncthreads();
        // ---- MFMA: 4 K-steps of 32 over this tile ----
        #pragma unroll
        for (int ks = 0; ks < 4; ++ks) {
            const int tb = ((ks * 64 + koff) ^ swz);
            const char* hA = reinterpret_cast<const char*>(ldsH) + (w * 16 + r) * (TT * 2) + tb;
            const char* lA = reinterpret_cast<const char*>(ldsL) + (w * 16 + r) * (TT * 2) + tb;
            const s16x8 ah = *reinterpret_cast<const s16x8*>(hA);
            const s16x8 al = *reinterpret_cast<const s16x8*>(lA);
            #pragma unroll
            for (int fn = 0; fn < 4; ++fn) {
                const int rowb = fn * 16 + r;
                const char* hB = reinterpret_cast<const char*>(ldsH) + rowb * (TT * 2) + tb;
                const char* lB = reinterpret_cast<const char*>(ldsL) + rowb * (TT * 2) + tb;
                const s16x8 bh = *reinterpret_cast<const s16x8*>(hB);
                const s16x8 bl = *reinterpret_cast<const s16x8*>(lB);
                acc[fn] = __builtin_amdgcn_mfma_f32_16x16x32_bf16(ah, bh, acc[fn], 0, 0, 0);
                acc[fn] = __builtin_amdgcn_mfma_f32_16x16x32_bf16(ah, bl, acc[fn], 0, 0, 0);
                acc[fn] = __builtin_amdgcn_mfma_f32_16x16x32_bf16(al, bh, acc[fn], 0, 0, 0);
            }
        }
    }

    // ---- S reduction: ssum[p] belongs to channel p*16+sch, partial over sg ----
    __syncthreads();   // all LDS fragment reads done; reuse ldsH as f32 scratch
    float* sred = reinterpret_cast<float*>(ldsH);   // 4*256 floats = 4 KB
    #pragma unroll
    for (int p = 0; p < 4; ++p) sred[p * 256 + tid] = ssum[p];
    __syncthreads();
    if (tid < NCH) {
        const int pidx = tid >> 4, ridx = tid & 15;
        float s = 0.f;
        #pragma unroll
        for (int g = 0; g < 16; ++g) s += sred[pidx * 256 + ridx * 16 + g];
        S[(size_t)(b * split + c) * NCH + tid] = s;
    }

    // ---- P write: D layout col=lane&15, row=(lane>>4)*4+reg ----
    float* Pc = P + ((size_t)(b * split + c) << 12);
    const int rowc = w * 16 + ((lane >> 4) << 2);
    const int col  = lane & 15;
    #pragma unroll
    for (int fn = 0; fn < 4; ++fn)
        #pragma unroll
        for (int reg = 0; reg < 4; ++reg)
            Pc[(rowc + reg) * 64 + fn * 16 + col] = acc[fn][reg];
}

// ---------------------------------------------------------------------------
// Stage 2: combine chunk partials -> corr -> threshold -> adj
// ---------------------------------------------------------------------------
__global__ __launch_bounds__(256) void corr_stage2(
    const float* __restrict__ P, const float* __restrict__ S,
    float* __restrict__ adj, int split)
{
    const int idx = blockIdx.x * 256 + threadIdx.x;   // < 128*4096
    const int b  = idx >> 12;
    const int nm = idx & 4095;
    const int n  = nm >> 6;
    const int m  = nm & 63;

    float G = 0.f, Gnn = 0.f, Gmm = 0.f, Sn = 0.f, Sm = 0.f;
    for (int c = 0; c < split; ++c) {
        const float* Pc = P + ((size_t)(b * split + c) << 12);
        const float* Sc = S + (size_t)(b * split + c) * NCH;
        G   += Pc[nm];
        Gnn += Pc[n * 65];
        Gmm += Pc[m * 65];
        Sn  += Sc[n];
        Sm  += Sc[m];
    }
    const float invT = 1.0f / (float)T_;
    const float cov  = G   - Sn * Sm * invT;
    const float vn   = Gnn - Sn * Sn * invT;
    const float vm   = Gmm - Sm * Sm * invT;
    const float den  = sqrtf(vn) * sqrtf(vm) + EPSF;
    float corr = cov / den;
    if (n == m) corr = 0.f;
    adj[idx] = (fabsf(corr) >= THRF) ? corr : 0.f;
}

// ---------------------------------------------------------------------------
extern "C" void kernel_launch(void* const* d_in, const int* in_sizes, int n_in,
                              void* d_out, int out_size, void* d_ws, size_t ws_size,
                              hipStream_t stream)
{
    const float* x   = (const float*)d_in[0];
    float* out   = (float*)d_out;
    float* adj   = out;                                  // 128*64*64
    float* out_x = out + (size_t)B_ * NCH * NCH;         // passthrough x

    // workspace: P = [128*split][4096] f32, S = [128*split][64] f32
    int split = 8;
    while (split > 1 &&
           (size_t)B_ * split * (4096 + NCH) * sizeof(float) > ws_size)
        split >>= 1;

    float* P = (float*)d_ws;
    float* S = P + (size_t)B_ * split * 4096;
    const int Tc = T_ / split;

    corr_stage1<<<dim3(B_ * split), dim3(256), 0, stream>>>(x, out_x, P, S, split, Tc);
    corr_stage2<<<dim3((B_ * 4096) / 256), dim3(256), 0, stream>>>(P, S, adj, split);
}